// Round 6
// baseline (106.729 us; speedup 1.0000x reference)
//
#include <hip/hip_runtime.h>

typedef float  f32x4  __attribute__((ext_vector_type(4)));
typedef float  f32x2  __attribute__((ext_vector_type(2)));
typedef short  bf16x8 __attribute__((ext_vector_type(8)));
typedef int    i32x4  __attribute__((ext_vector_type(4)));

#define NNODE 3072
#define DIN   128
#define DOUT  128
#define NREL  3
#define NH    4
#define HD    32
#define KCH   48      // K chunks of 64
#define CHB   9216    // ushorts per B chunk (9 tiles * 2 steps * 64 lanes * 8)

static __device__ __forceinline__ unsigned short f2bf(float v) {
  unsigned u = __builtin_bit_cast(unsigned, v);
  u += 0x7FFFu + ((u >> 16) & 1u);          // round-to-nearest-even
  return (unsigned short)(u >> 16);
}

// ---------------- K0: init out = bias ----------------
__global__ __launch_bounds__(256, 1) void k0_init(
    const float* __restrict__ bias, float* __restrict__ out)
{
  const int tid = blockIdx.x * 256 + threadIdx.x;   // 3072*128/4 elems
  f32x4 b = *(const f32x4*)(bias + (tid & 31) * 4);
  *((f32x4*)out + tid) = b;
}

// ---------------- K1: t = F * W_r^T, attention scalars, build B in MFMA-fragment order ----
// grid (48, 3), block 256. Each block: one relation, 64 k-rows (= one 64-K chunk). (validated)
__global__ __launch_bounds__(256, 1) void k1_prep(
    const float* __restrict__ feat, const float* __restrict__ W,
    const float* __restrict__ av, unsigned short* __restrict__ Mt,
    float* __restrict__ Es)
{
  const int jt = blockIdx.x;     // 0..47  (= K chunk index)
  const int r  = blockIdx.y;     // 0..2
  const int t  = threadIdx.x;    // 0..255
  const int jb = jt * 64;

  __shared__ float Wl[128 * 130];
  __shared__ float Fl[64 * 129];
  __shared__ float Tl[64 * 129];
  __shared__ float El[64 * 5];

  const float* Wr = W + r * DOUT * DIN;
  for (int idx = t * 4; idx < DOUT * DIN; idx += 1024) {
    float4 v = *(const float4*)(Wr + idx);
    int o = idx >> 7, k = idx & 127;
    float* d = Wl + o * 130 + k;
    d[0] = v.x; d[1] = v.y; d[2] = v.z; d[3] = v.w;
  }
  for (int idx = t * 4; idx < 64 * DIN; idx += 1024) {
    float4 v = *(const float4*)(feat + (size_t)jb * DIN + idx);
    int n = idx >> 7, k = idx & 127;
    float* d = Fl + n * 129 + k;
    d[0] = v.x; d[1] = v.y; d[2] = v.z; d[3] = v.w;
  }
  __syncthreads();

  {
    const int ng = t & 15, og = t >> 4;
    float acc[4][8] = {};
    for (int k = 0; k < DIN; k += 4) {
      float wv[4][8];
      #pragma unroll
      for (int oo = 0; oo < 8; ++oo) {
        const float* wr2 = Wl + (og * 8 + oo) * 130 + k;
        f32x2 a01 = *(const f32x2*)wr2;
        f32x2 a23 = *(const f32x2*)(wr2 + 2);
        wv[0][oo] = a01[0]; wv[1][oo] = a01[1];
        wv[2][oo] = a23[0]; wv[3][oo] = a23[1];
      }
      #pragma unroll
      for (int nn = 0; nn < 4; ++nn) {
        const float* fr = Fl + (ng * 4 + nn) * 129 + k;
        float f0 = fr[0], f1 = fr[1], f2 = fr[2], f3 = fr[3];
        #pragma unroll
        for (int oo = 0; oo < 8; ++oo) {
          float s = acc[nn][oo];
          s = fmaf(f0, wv[0][oo], s);
          s = fmaf(f1, wv[1][oo], s);
          s = fmaf(f2, wv[2][oo], s);
          s = fmaf(f3, wv[3][oo], s);
          acc[nn][oo] = s;
        }
      }
    }
    #pragma unroll
    for (int nn = 0; nn < 4; ++nn)
      #pragma unroll
      for (int oo = 0; oo < 8; ++oo)
        Tl[(ng * 4 + nn) * 129 + og * 8 + oo] = acc[nn][oo];
  }
  __syncthreads();

  {
    const int n = t & 63, h = t >> 6;
    const float* tr = Tl + n * 129 + h * HD;
    const float* as = av + r * 2 * HD;
    float ss = 0.f, sd = 0.f;
    #pragma unroll
    for (int d = 0; d < HD; ++d) {
      float tvv = tr[d];
      ss = fmaf(tvv, as[d],      ss);
      sd = fmaf(tvv, as[HD + d], sd);
    }
    Es[((size_t)r * NNODE + jb + n) * NH + h] = expf(ss);
    El[n * 5 + h] = expf(sd);
  }
  __syncthreads();

  {
    // B fragment order: chunk = [tile nt][step s][lane = k8*16 + (c&15)][elem = j&7]
    const int n = t & 63, cb = t >> 6;   // j = jb + n
    unsigned short* base = Mt + ((size_t)r * KCH + jt) * CHB;
    const int s = n >> 5, k8 = (n >> 3) & 3, elem = n & 7;
    const int lanebase = k8 * 16;
    #pragma unroll
    for (int ci = 0; ci < 36; ++ci) {
      int c = cb * 36 + ci;
      float v;
      if (c < DOUT)            v = Tl[n * 129 + c] * El[n * 5 + (c >> 5)];
      else if (c < DOUT + NH)  v = El[n * 5 + (c - DOUT)];
      else if (c == DOUT + NH) v = 1.0f;
      else                     v = 0.0f;
      int nt = c >> 4;
      base[(nt * 2 + s) * 512 + (lanebase + (c & 15)) * 8 + elem] = f2bf(v);
    }
  }
}

// ---------------- K2: all-LDS-staged pipelined A@M, fused finalize ----------------
// grid (192, 3), block 256 = 4 waves. Block: 16 rows x 144 cols, full K (48 chunks).
// Waves SPLIT N: wave w owns tiles {2w, 2w+1} (+ tile 8 for wave 0). A and B both staged
// via global_load_lds (no VGPR staging at all). Per iter per wave: 4-5 B-stage + 1 A-stage
// DMA instrs issued right after the barrier; counted wait vmcnt(1); 3 A-bufs / 2 B-bufs.
__global__ __launch_bounds__(256, 2) void k2_agg(
    const int* __restrict__ adj, const unsigned short* __restrict__ Mt,
    const float* __restrict__ Es, float* __restrict__ out)
{
  const int it = blockIdx.x;    // 0..191
  const int r  = blockIdx.y;    // 0..2
  const int t  = threadIdx.x;   // 0..255
  const int wv = t >> 6;        // 0..3
  const int l  = t & 63;
  const int l16 = l & 15, l4 = l >> 4;
  const int ib = it * 16;

  __shared__ __align__(16) int            Abuf[3][1024];   // 3 x 4KB  (16 rows x 64 ints, XOR swz)
  __shared__ __align__(16) unsigned short Bbuf[2][CHB];    // 2 x 18KB (fragment-linear)
  __shared__ float red[16 * 145];
  __shared__ float coefL[64];

  // A stage: thread t -> row t>>4, 16B chunk (t&15)^(row&7); dest = linear t*16B.
  const size_t adjBase = (size_t)r * NNODE * NNODE + (size_t)ib * NNODE;
  const int arow = t >> 4;
  const int* asrc = adj + adjBase + (size_t)arow * NNODE + ((t & 15) ^ (arow & 7)) * 4;

  const unsigned short* msrc = Mt + (size_t)r * KCH * CHB;

  #define STAGE_A(kc, buf)                                                        \
    __builtin_amdgcn_global_load_lds(                                             \
        (const __attribute__((address_space(1))) void*)(asrc + (kc) * 64),        \
        (__attribute__((address_space(3))) void*)&Abuf[buf][t * 4], 16, 0, 0)

  #define STAGE_B(kc, buf) do {                                                   \
    const unsigned short* bs_ = msrc + (size_t)(kc) * CHB;                        \
    _Pragma("unroll")                                                             \
    for (int j_ = 0; j_ < 4; ++j_)                                                \
      __builtin_amdgcn_global_load_lds(                                           \
        (const __attribute__((address_space(1))) void*)(bs_ + (j_ * 256 + t) * 8),\
        (__attribute__((address_space(3))) void*)&Bbuf[buf][(j_ * 256 + t) * 8],  \
        16, 0, 0);                                                                \
    if (t < 128)                                                                  \
      __builtin_amdgcn_global_load_lds(                                           \
        (const __attribute__((address_space(1))) void*)(bs_ + (1024 + t) * 8),    \
        (__attribute__((address_space(3))) void*)&Bbuf[buf][(1024 + t) * 8],      \
        16, 0, 0);                                                                \
  } while (0)

  const int tb = wv * 2;            // tile base: 0,2,4,6 ; wave 0 also owns tile 8
  f32x4 acc0 = {}, acc1 = {}, acc2 = {};
  const int xm = (l & 7) << 2;

  // prologue: chunk 0 (A+B) and chunk 1 (A) in flight
  STAGE_A(0, 0);
  STAGE_B(0, 0);
  STAGE_A(1, 1);

  #pragma unroll 1
  for (int k = 0; k < KCH; ++k) {
    // wait: all of MY chunk-k loads done (FIFO: only newest A-stage may remain)
    asm volatile("s_waitcnt vmcnt(1)");
    __builtin_amdgcn_sched_barrier(0);
    __builtin_amdgcn_s_barrier();
    __builtin_amdgcn_sched_barrier(0);

    // issue next stages FIRST (buffers freed by the barrier): B(k+1), then A(k+2)
    {
      const int nb = (k + 1 < KCH) ? k + 1 : KCH - 1;
      const int na = (k + 2 < KCH) ? k + 2 : KCH - 1;
      STAGE_B(nb, (k + 1) & 1);
      STAGE_A(na, (k + 2) % 3);
    }

    const int ab = k % 3, bb = k & 1;
    #pragma unroll
    for (int s = 0; s < 2; ++s) {
      const int ko = s * 32 + l4 * 8;
      i32x4 a0 = *(const i32x4*)&Abuf[ab][l16 * 64 + ((ko + 0) ^ xm)];
      i32x4 a1 = *(const i32x4*)&Abuf[ab][l16 * 64 + ((ko + 4) ^ xm)];
      bf16x8 af = __builtin_bit_cast(bf16x8, (i32x4){
        (a0[0] | (a0[1] << 16)) * 0x3F80, (a0[2] | (a0[3] << 16)) * 0x3F80,
        (a1[0] | (a1[1] << 16)) * 0x3F80, (a1[2] | (a1[3] << 16)) * 0x3F80 });
      bf16x8 b0 = *(const bf16x8*)&Bbuf[bb][((tb + 0) * 2 + s) * 512 + l * 8];
      acc0 = __builtin_amdgcn_mfma_f32_16x16x32_bf16(af, b0, acc0, 0, 0, 0);
      bf16x8 b1 = *(const bf16x8*)&Bbuf[bb][((tb + 1) * 2 + s) * 512 + l * 8];
      acc1 = __builtin_amdgcn_mfma_f32_16x16x32_bf16(af, b1, acc1, 0, 0, 0);
      if (wv == 0) {
        bf16x8 b2 = *(const bf16x8*)&Bbuf[bb][(8 * 2 + s) * 512 + l * 8];
        acc2 = __builtin_amdgcn_mfma_f32_16x16x32_bf16(af, b2, acc2, 0, 0, 0);
      }
    }
  }

  // ---- epilogue: waves own disjoint col-tiles -> plain writes, no K-reduction ----
  #pragma unroll
  for (int rg = 0; rg < 4; ++rg) {
    red[(l4 * 4 + rg) * 145 + (tb + 0) * 16 + l16] = acc0[rg];
    red[(l4 * 4 + rg) * 145 + (tb + 1) * 16 + l16] = acc1[rg];
    if (wv == 0)
      red[(l4 * 4 + rg) * 145 + 8 * 16 + l16] = acc2[rg];
  }
  __syncthreads();

  if (t < 64) {
    int row = t >> 2, h = t & 3;
    float es = Es[((size_t)r * NNODE + ib + row) * NH + h];
    float V  = red[row * 145 + DOUT + h];
    float dg = red[row * 145 + DOUT + NH];
    coefL[t] = es / fmaf(es, V, (float)NNODE - dg) * (1.0f / NREL);
  }
  __syncthreads();

  #pragma unroll
  for (int idx = t; idx < 16 * DOUT; idx += 256) {
    int row = idx >> 7, c = idx & 127;
    atomicAdd(&out[(size_t)(ib + row) * DOUT + c],
              coefL[row * 4 + (c >> 5)] * red[row * 145 + c]);
  }
  #undef STAGE_A
  #undef STAGE_B
}

extern "C" void kernel_launch(void* const* d_in, const int* in_sizes, int n_in,
                              void* d_out, int out_size, void* d_ws, size_t ws_size,
                              hipStream_t stream) {
  const float* feat = (const float*)d_in[0];
  const int*   adj  = (const int*)d_in[1];
  const float* W    = (const float*)d_in[2];
  const float* av   = (const float*)d_in[3];
  const float* bias = (const float*)d_in[4];

  char* ws = (char*)d_ws;
  unsigned short* Mt = (unsigned short*)ws;                 // 3*48*9216*2  = 2,654,208 B
  float* Es = (float*)(ws + 2654208);                       // 3*3072*4*4   =   147,456 B
                                                            // total ws use: 2,801,664 B

  hipLaunchKernelGGL(k0_init, dim3(384), dim3(256), 0, stream, bias, (float*)d_out);
  hipLaunchKernelGGL(k1_prep, dim3(48, 3), dim3(256), 0, stream, feat, W, av, Mt, Es);
  hipLaunchKernelGGL(k2_agg,  dim3(192, 3), dim3(256), 0, stream, adj, Mt, Es, (float*)d_out);
}

// Round 8
// 78.767 us; speedup vs baseline: 1.3550x; 1.3550x over previous
//
#include <hip/hip_runtime.h>

typedef float  f32x4  __attribute__((ext_vector_type(4)));
typedef float  f32x2  __attribute__((ext_vector_type(2)));
typedef short  bf16x8 __attribute__((ext_vector_type(8)));
typedef int    i32x4  __attribute__((ext_vector_type(4)));

#define NNODE 3072
#define DIN   128
#define DOUT  128
#define NREL  3
#define NH    4
#define HD    32
#define KCH   48      // K chunks of 64
#define CHB   9216    // ushorts per B chunk (9 tiles * 2 steps * 64 lanes * 8)

static __device__ __forceinline__ unsigned short f2bf(float v) {
  unsigned u = __builtin_bit_cast(unsigned, v);
  u += 0x7FFFu + ((u >> 16) & 1u);          // round-to-nearest-even
  return (unsigned short)(u >> 16);
}

// ---------------- K0: init out = bias ----------------
__global__ __launch_bounds__(256, 1) void k0_init(
    const float* __restrict__ bias, float* __restrict__ out)
{
  const int tid = blockIdx.x * 256 + threadIdx.x;   // 3072*128/4 elems
  f32x4 b = *(const f32x4*)(bias + (tid & 31) * 4);
  *((f32x4*)out + tid) = b;
}

// ---------------- K1: t = F * W_r^T, attention scalars, build B in MFMA-fragment order ----
// grid (48, 3), block 256. (numerics validated R2-R6)
__global__ __launch_bounds__(256, 1) void k1_prep(
    const float* __restrict__ feat, const float* __restrict__ W,
    const float* __restrict__ av, unsigned short* __restrict__ Mt,
    float* __restrict__ Es)
{
  const int jt = blockIdx.x;     // 0..47  (= K chunk index)
  const int r  = blockIdx.y;     // 0..2
  const int t  = threadIdx.x;    // 0..255
  const int jb = jt * 64;

  __shared__ float Wl[128 * 130];
  __shared__ float Fl[64 * 129];
  __shared__ float Tl[64 * 129];
  __shared__ float El[64 * 5];

  const float* Wr = W + r * DOUT * DIN;
  for (int idx = t * 4; idx < DOUT * DIN; idx += 1024) {
    float4 v = *(const float4*)(Wr + idx);
    int o = idx >> 7, k = idx & 127;
    float* d = Wl + o * 130 + k;
    d[0] = v.x; d[1] = v.y; d[2] = v.z; d[3] = v.w;
  }
  for (int idx = t * 4; idx < 64 * DIN; idx += 1024) {
    float4 v = *(const float4*)(feat + (size_t)jb * DIN + idx);
    int n = idx >> 7, k = idx & 127;
    float* d = Fl + n * 129 + k;
    d[0] = v.x; d[1] = v.y; d[2] = v.z; d[3] = v.w;
  }
  __syncthreads();

  {
    const int ng = t & 15, og = t >> 4;
    float acc[4][8] = {};
    for (int k = 0; k < DIN; k += 4) {
      float wv[4][8];
      #pragma unroll
      for (int oo = 0; oo < 8; ++oo) {
        const float* wr2 = Wl + (og * 8 + oo) * 130 + k;
        f32x2 a01 = *(const f32x2*)wr2;
        f32x2 a23 = *(const f32x2*)(wr2 + 2);
        wv[0][oo] = a01[0]; wv[1][oo] = a01[1];
        wv[2][oo] = a23[0]; wv[3][oo] = a23[1];
      }
      #pragma unroll
      for (int nn = 0; nn < 4; ++nn) {
        const float* fr = Fl + (ng * 4 + nn) * 129 + k;
        float f0 = fr[0], f1 = fr[1], f2 = fr[2], f3 = fr[3];
        #pragma unroll
        for (int oo = 0; oo < 8; ++oo) {
          float s = acc[nn][oo];
          s = fmaf(f0, wv[0][oo], s);
          s = fmaf(f1, wv[1][oo], s);
          s = fmaf(f2, wv[2][oo], s);
          s = fmaf(f3, wv[3][oo], s);
          acc[nn][oo] = s;
        }
      }
    }
    #pragma unroll
    for (int nn = 0; nn < 4; ++nn)
      #pragma unroll
      for (int oo = 0; oo < 8; ++oo)
        Tl[(ng * 4 + nn) * 129 + og * 8 + oo] = acc[nn][oo];
  }
  __syncthreads();

  {
    const int n = t & 63, h = t >> 6;
    const float* tr = Tl + n * 129 + h * HD;
    const float* as = av + r * 2 * HD;
    float ss = 0.f, sd = 0.f;
    #pragma unroll
    for (int d = 0; d < HD; ++d) {
      float tvv = tr[d];
      ss = fmaf(tvv, as[d],      ss);
      sd = fmaf(tvv, as[HD + d], sd);
    }
    Es[((size_t)r * NNODE + jb + n) * NH + h] = expf(ss);
    El[n * 5 + h] = expf(sd);
  }
  __syncthreads();

  {
    // B fragment order: chunk = [tile nt][step s][lane = k8*16 + (c&15)][elem = j&7]
    const int n = t & 63, cb = t >> 6;   // j = jb + n
    unsigned short* base = Mt + ((size_t)r * KCH + jt) * CHB;
    const int s = n >> 5, k8 = (n >> 3) & 3, elem = n & 7;
    const int lanebase = k8 * 16;
    #pragma unroll
    for (int ci = 0; ci < 36; ++ci) {
      int c = cb * 36 + ci;
      float v;
      if (c < DOUT)            v = Tl[n * 129 + c] * El[n * 5 + (c >> 5)];
      else if (c < DOUT + NH)  v = El[n * 5 + (c - DOUT)];
      else if (c == DOUT + NH) v = 1.0f;
      else                     v = 0.0f;
      int nt = c >> 4;
      base[(nt * 2 + s) * 512 + (lanebase + (c & 15)) * 8 + elem] = f2bf(v);
    }
  }
}

// ---------------- K2a: bit-pack adjacency (113 MB -> 3.5 MB), pure HBM stream ----------------
// grid 2048, block 256 (= 8192 waves x 54 units). unit = one 64-col span of one row.
__global__ __launch_bounds__(256) void k2a_pack(
    const int* __restrict__ adj, unsigned int* __restrict__ pk)
{
  const int wgid = blockIdx.x * 4 + (threadIdx.x >> 6);
  const int l = threadIdx.x & 63;
  #pragma unroll 1
  for (int i = 0; i < 54; ++i) {
    const int u = i * 8192 + wgid;            // 0..442367
    const int rrow = u / 48, c64 = u - rrow * 48;
    int a = adj[(size_t)rrow * NNODE + c64 * 64 + l];
    unsigned long long m = __ballot(a != 0);
    if (l == 0)
      *(unsigned long long*)(pk + (size_t)rrow * 96 + c64 * 2) = m;
  }
}

// ---------------- K2b: barrier-free GEMM on bitpacked A, asm-pipelined B, fused finalize ----
// grid (96, 3), block 256 = 4 waves. Block: 32 rows x 144 cols, full K.
// A (12KB packed) resident in LDS after prologue. B double-buffered in named asm regs;
// counted vmcnt with register data-threading (compiler waitcnt pass sees NO loop memory ops).
#define GLO(dst, p, off) \
  asm volatile("global_load_dwordx4 %0, %1, off offset:" off : "=v"(dst) : "v"(p))

// NOTE: bit-spread multiplier trick is only carry-free for a 4-bit multiplicand
// (shift gap 7 >= width 4). R7 bug: fed full 8-bit byte -> carries corrupted bits.
#define EXPAND(d, dst) do {                                                \
    unsigned b_  = ((d) >> sh) & 0xFFu;                                    \
    unsigned lo_ = ((b_ & 0x0Fu) * 0x204081u) & 0x01010101u;               \
    unsigned hi_ = ((b_ >> 4)   * 0x204081u) & 0x01010101u;                \
    dst = __builtin_bit_cast(bf16x8, (i32x4){                              \
      (int)(__builtin_amdgcn_perm(0u, lo_, 0x0C010C00u) * 0x3F80u),        \
      (int)(__builtin_amdgcn_perm(0u, lo_, 0x0C030C02u) * 0x3F80u),        \
      (int)(__builtin_amdgcn_perm(0u, hi_, 0x0C010C00u) * 0x3F80u),        \
      (int)(__builtin_amdgcn_perm(0u, hi_, 0x0C030C02u) * 0x3F80u)});      \
  } while (0)

#define MF(a, b, c) __builtin_amdgcn_mfma_f32_16x16x32_bf16(a, __builtin_bit_cast(bf16x8, b), c, 0, 0, 0)

__global__ __launch_bounds__(256, 2) void k2b_agg(
    const unsigned int* __restrict__ pk, const unsigned short* __restrict__ Mt,
    const float* __restrict__ Es, float* __restrict__ out)
{
  const int it = blockIdx.x;    // 0..95
  const int r  = blockIdx.y;    // 0..2
  const int t  = threadIdx.x;   // 0..255
  const int wv = t >> 6;
  const int l  = t & 63;
  const int l16 = l & 15, l4 = l >> 4;
  const int ib = it * 32;
  const bool w3 = (wv == 3);
  const unsigned sh = (unsigned)l4 * 8u;

  __shared__ unsigned Al[32 * 97];    // packed A bits, bank-padded (97)
  __shared__ float red[32 * 145];
  __shared__ float coefL[128];

  // ---- prologue: whole A row-block (all K) into LDS once ----
  {
    const unsigned* pg = pk + ((size_t)r * NNODE + ib) * 96;
    #pragma unroll
    for (int x = 0; x < 12; ++x) {
      int idx = t + x * 256;
      Al[(idx / 96) * 97 + (idx % 96)] = pg[idx];
    }
  }
  __syncthreads();

  // wave wv owns col-tiles {2wv, 2wv+1}; wave 3 also tile 8 (V/deg).
  const unsigned short* bpw = Mt + (size_t)r * KCH * CHB + (size_t)(wv * 4) * 512 + (size_t)l * 8;

  i32x4 A0={},A1={},A2={},A3={},A4={},A5={};
  i32x4 B0={},B1={},B2={},B3={},B4={},B5={};
  f32x4 acc00={}, acc01={}, acc10={}, acc11={}, acc20={}, acc21={};

  // prologue B: chunk 0 into A-set
  {
    const unsigned short* p0 = bpw;
    GLO(A0, p0, "0"); GLO(A1, p0, "1024"); GLO(A2, p0, "2048"); GLO(A3, p0, "3072");
    if (w3) { const unsigned short* p4 = p0 + 2048; GLO(A4, p4, "0"); GLO(A5, p4, "1024"); }
  }

  #define STEP(kc, X0,X1,X2,X3,X4,X5, Y0,Y1,Y2,Y3,Y4,Y5) do {              \
    const int nk_ = ((kc) + 1 < KCH) ? (kc) + 1 : KCH - 1;                  \
    const unsigned short* np_ = bpw + (size_t)nk_ * CHB;                    \
    GLO(Y0, np_, "0"); GLO(Y1, np_, "1024");                                \
    GLO(Y2, np_, "2048"); GLO(Y3, np_, "3072");                             \
    if (w3) { const unsigned short* n4_ = np_ + 2048;                       \
              GLO(Y4, n4_, "0"); GLO(Y5, n4_, "1024"); }                    \
    const int c2_ = 2 * (kc);                                               \
    unsigned d00_ = Al[l16 * 97 + c2_],        d01_ = Al[l16 * 97 + c2_ + 1]; \
    unsigned d10_ = Al[(16 + l16) * 97 + c2_], d11_ = Al[(16 + l16) * 97 + c2_ + 1]; \
    bf16x8 af0_, af1_;                                                      \
    EXPAND(d00_, af0_); EXPAND(d10_, af1_);                                 \
    if (w3) { asm volatile("s_waitcnt vmcnt(6)"                             \
        : "+v"(X0), "+v"(X1), "+v"(X2), "+v"(X3), "+v"(X4), "+v"(X5)); }    \
    else    { asm volatile("s_waitcnt vmcnt(4)"                             \
        : "+v"(X0), "+v"(X1), "+v"(X2), "+v"(X3)); }                        \
    __builtin_amdgcn_sched_barrier(0);                                      \
    acc00 = MF(af0_, X0, acc00); acc01 = MF(af1_, X0, acc01);               \
    acc10 = MF(af0_, X2, acc10); acc11 = MF(af1_, X2, acc11);               \
    if (w3) { acc20 = MF(af0_, X4, acc20); acc21 = MF(af1_, X4, acc21); }   \
    EXPAND(d01_, af0_); EXPAND(d11_, af1_);                                 \
    acc00 = MF(af0_, X1, acc00); acc01 = MF(af1_, X1, acc01);               \
    acc10 = MF(af0_, X3, acc10); acc11 = MF(af1_, X3, acc11);               \
    if (w3) { acc20 = MF(af0_, X5, acc20); acc21 = MF(af1_, X5, acc21); }   \
  } while (0)

  #pragma unroll 1
  for (int k = 0; k < KCH; k += 2) {
    STEP(k,     A0,A1,A2,A3,A4,A5,  B0,B1,B2,B3,B4,B5);
    STEP(k + 1, B0,B1,B2,B3,B4,B5,  A0,A1,A2,A3,A4,A5);
  }
  // retire dangling prefetch (keeps regs live until HW writes them)
  asm volatile("s_waitcnt vmcnt(0)"
      : "+v"(A0), "+v"(A1), "+v"(A2), "+v"(A3), "+v"(A4), "+v"(A5));
  #undef STEP

  // ---- epilogue: disjoint col-tiles -> plain LDS writes, coef, atomic out ----
  const int tc0 = wv * 2;
  #pragma unroll
  for (int j = 0; j < 4; ++j) {
    red[(l4 * 4 + j) * 145 + (tc0 + 0) * 16 + l16]      = acc00[j];
    red[(16 + l4 * 4 + j) * 145 + (tc0 + 0) * 16 + l16] = acc01[j];
    red[(l4 * 4 + j) * 145 + (tc0 + 1) * 16 + l16]      = acc10[j];
    red[(16 + l4 * 4 + j) * 145 + (tc0 + 1) * 16 + l16] = acc11[j];
    if (w3) {
      red[(l4 * 4 + j) * 145 + 8 * 16 + l16]      = acc20[j];
      red[(16 + l4 * 4 + j) * 145 + 8 * 16 + l16] = acc21[j];
    }
  }
  __syncthreads();

  if (t < 128) {
    int row = t >> 2, h = t & 3;
    float es = Es[((size_t)r * NNODE + ib + row) * NH + h];
    float V  = red[row * 145 + DOUT + h];
    float dg = red[row * 145 + DOUT + NH];
    coefL[t] = es / fmaf(es, V, (float)NNODE - dg) * (1.0f / NREL);
  }
  __syncthreads();

  #pragma unroll
  for (int idx = t; idx < 32 * DOUT; idx += 256) {
    int row = idx >> 7, c = idx & 127;
    atomicAdd(&out[(size_t)(ib + row) * DOUT + c],
              coefL[row * 4 + (c >> 5)] * red[row * 145 + c]);
  }
}

// ---------------- K2fb: fallback (R5-validated) if ws is too small for pk ----------------
__global__ __launch_bounds__(256, 3) void k2_fb(
    const int* __restrict__ adj, const unsigned short* __restrict__ Mt,
    const float* __restrict__ Es, float* __restrict__ out)
{
  const int it = blockIdx.x;
  const int r  = blockIdx.y;
  const int t  = threadIdx.x;
  const int wv = t >> 6;
  const int l  = t & 63;
  const int l16 = l & 15, l4 = l >> 4;
  const int ib = it * 16;

  __shared__ __align__(16) int Ash[4][2][1024];
  __shared__ float red[16 * 145];
  __shared__ float coefL[64];

  const size_t adjBase = (size_t)r * NNODE * NNODE + (size_t)ib * NNODE;
  const int* asrc[4];
  #pragma unroll
  for (int q = 0; q < 4; ++q) {
    int row = q * 4 + l4;
    int chk = l16 ^ (row & 7);
    asrc[q] = adj + adjBase + (size_t)row * NNODE + wv * 64 + chk * 4;
  }
  const unsigned short* bp = Mt + (size_t)r * KCH * CHB + (size_t)wv * CHB + (size_t)l * 8;

  f32x4 acc[9] = {};
  bf16x8 B[9][2];
  int zero = 0;

  #define STAGE(bufi) do {                                                        \
    _Pragma("unroll")                                                             \
    for (int q = 0; q < 4; ++q)                                                   \
      __builtin_amdgcn_global_load_lds(                                           \
        (const __attribute__((address_space(1))) void*)asrc[q],                   \
        (__attribute__((address_space(3))) void*)&Ash[wv][bufi][q * 256], 16, 0, 0); \
  } while (0)

  STAGE(0);

  #pragma unroll 1
  for (int k = 0; k < 12; ++k) {
    #pragma unroll
    for (int ti = 0; ti < 9; ++ti) {
      B[ti][0] = *(const bf16x8*)(bp + (ti * 2 + 0) * 512);
      B[ti][1] = *(const bf16x8*)(bp + (ti * 2 + 1) * 512);
    }
    bp += 4 * CHB;
    __builtin_amdgcn_sched_barrier(0);

    const int adv = (k < 11) ? 256 : 0;
    #pragma unroll
    for (int q = 0; q < 4; ++q) asrc[q] += adv;
    STAGE((k + 1) & 1);

    asm volatile("s_waitcnt vmcnt(4)" : "+v"(zero));
    __builtin_amdgcn_sched_barrier(0);

    const int* Ab = (const int*)((const char*)&Ash[wv][k & 1][0] + zero);
    #pragma unroll
    for (int s = 0; s < 2; ++s) {
      const int ko = s * 32 + l4 * 8;
      const int xm = (l & 7) << 2;
      i32x4 a0 = *(const i32x4*)&Ab[l16 * 64 + ((ko + 0) ^ xm)];
      i32x4 a1 = *(const i32x4*)&Ab[l16 * 64 + ((ko + 4) ^ xm)];
      bf16x8 af = __builtin_bit_cast(bf16x8, (i32x4){
        (a0[0] | (a0[1] << 16)) * 0x3F80, (a0[2] | (a0[3] << 16)) * 0x3F80,
        (a1[0] | (a1[1] << 16)) * 0x3F80, (a1[2] | (a1[3] << 16)) * 0x3F80 });
      #pragma unroll
      for (int ti = 0; ti < 9; ++ti)
        acc[ti] = __builtin_amdgcn_mfma_f32_16x16x32_bf16(af, B[ti][s], acc[ti], 0, 0, 0);
    }
  }
  #undef STAGE

  if (wv == 0) {
    #pragma unroll
    for (int ti = 0; ti < 9; ++ti)
      #pragma unroll
      for (int rg = 0; rg < 4; ++rg)
        red[(l4 * 4 + rg) * 145 + ti * 16 + l16] = acc[ti][rg];
  }
  __syncthreads();
  #pragma unroll 1
  for (int w = 1; w < 4; ++w) {
    if (wv == w) {
      #pragma unroll
      for (int ti = 0; ti < 9; ++ti)
        #pragma unroll
        for (int rg = 0; rg < 4; ++rg)
          red[(l4 * 4 + rg) * 145 + ti * 16 + l16] += acc[ti][rg];
    }
    __syncthreads();
  }

  if (t < 64) {
    int row = t >> 2, h = t & 3;
    float es = Es[((size_t)r * NNODE + ib + row) * NH + h];
    float V  = red[row * 145 + DOUT + h];
    float dg = red[row * 145 + DOUT + NH];
    coefL[t] = es / fmaf(es, V, (float)NNODE - dg) * (1.0f / NREL);
  }
  __syncthreads();

  #pragma unroll
  for (int idx = t; idx < 16 * DOUT; idx += 256) {
    int row = idx >> 7, c = idx & 127;
    atomicAdd(&out[(size_t)(ib + row) * DOUT + c],
              coefL[row * 4 + (c >> 5)] * red[row * 145 + c]);
  }
}

extern "C" void kernel_launch(void* const* d_in, const int* in_sizes, int n_in,
                              void* d_out, int out_size, void* d_ws, size_t ws_size,
                              hipStream_t stream) {
  const float* feat = (const float*)d_in[0];
  const int*   adj  = (const int*)d_in[1];
  const float* W    = (const float*)d_in[2];
  const float* av   = (const float*)d_in[3];
  const float* bias = (const float*)d_in[4];

  char* ws = (char*)d_ws;
  unsigned short* Mt = (unsigned short*)ws;                 // 2,654,208 B
  float* Es = (float*)(ws + 2654208);                       //   147,456 B
  unsigned int* pk = (unsigned int*)(ws + 2801664);         // 3,538,944 B  (total 6,340,608)

  hipLaunchKernelGGL(k0_init, dim3(384), dim3(256), 0, stream, bias, (float*)d_out);
  hipLaunchKernelGGL(k1_prep, dim3(48, 3), dim3(256), 0, stream, feat, W, av, Mt, Es);
  if (ws_size >= 6340608) {
    hipLaunchKernelGGL(k2a_pack, dim3(2048), dim3(256), 0, stream, adj, pk);
    hipLaunchKernelGGL(k2b_agg,  dim3(96, 3), dim3(256), 0, stream, pk, Mt, Es, (float*)d_out);
  } else {
    hipLaunchKernelGGL(k2_fb, dim3(192, 3), dim3(256), 0, stream, adj, Mt, Es, (float*)d_out);
  }
}